// Round 3
// baseline (136.443 us; speedup 1.0000x reference)
//
#include <hip/hip_runtime.h>
#include <math.h>

#define BDIM 8
#define NDIM 128
#define TDIM 1024
#define TPB 256   // 4 elements per thread, one pass

#define EPS_F 1e-12f
#define RHO_LIM_F (1.0f - 1e-6f)
#define PI_F 3.14159265358979323846f

// One block per (b1,b2,n) row of T=1024. Each thread owns 4 consecutive t.
// LDS arrays hold c0 / c1*k_ntk at index t+4 (16B-aligned per-thread float4
// stores); zero halos at index 3 (t=-1) and TDIM+4 (t=T).

__global__ __launch_bounds__(TPB) void conv_arccos_kernel(
    const float* __restrict__ k,      // (B,B,N,T,2)
    const float* __restrict__ leak,   // scalar
    const float* __restrict__ alpha,  // (3,)
    const float* __restrict__ beta,   // scalar
    float* __restrict__ out)          // (B,B,N,T,2)
{
    __shared__ __align__(16) float sc0[TDIM + 8];
    __shared__ __align__(16) float scn[TDIM + 8];

    const int row = blockIdx.x;           // 0 .. B*B*N-1
    const int n   = row % NDIM;
    const int bb  = row / NDIM;
    const int b2  = bb % BDIM;
    const int b1  = bb / BDIM;
    const int tid = threadIdx.x;
    const int t   = tid * 4;

    // forward value of clamp_pg(x) is max(x, 0)
    const float a   = fmaxf(leak[0], 0.0f);
    const float w0  = fmaxf(alpha[0], 0.0f);
    const float w1  = fmaxf(alpha[1], 0.0f);
    const float w2  = fmaxf(alpha[2], 0.0f);
    const float bia = fmaxf(beta[0], 0.0f);

    const float one_m  = (1.0f - a) * (1.0f - a);
    const float coef   = 1.0f + a * a;
    const float inv2pi = 0.15915494309189535f;

    const float4* krow4 = (const float4*)(k + (size_t)row * TDIM * 2);
    // v[b, t] = k[b, b, 0, t, 0]
    const float2* vrx = (const float2*)(k) + (size_t)(b1 * BDIM + b1) * NDIM * TDIM;
    const float2* vry = (const float2*)(k) + (size_t)(b2 * BDIM + b2) * NDIM * TDIM;

    // zero conv halos
    if (tid == 0) { sc0[3] = 0.0f; scn[3] = 0.0f; }
    if (tid == 1) { sc0[TDIM + 4] = 0.0f; scn[TDIM + 4] = 0.0f; }

    // ---- phase 1: elementwise transform, 4 elems/thread ----
    const float4 kvA = krow4[2 * tid];       // t, t+1   (kgp,kntk pairs)
    const float4 kvB = krow4[2 * tid + 1];   // t+2, t+3
    const float4 vxA = ((const float4*)vrx)[2 * tid];      // vx[t] (.x), vx[t+1] (.z)
    const float4 vxB = ((const float4*)vrx)[2 * tid + 1];

    const int lim = TDIM - n;  // vy in-bounds iff t+i < lim
    const float vy0 = (t     < lim) ? vry[n + t    ].x : 0.0f;
    const float vy1 = (t + 1 < lim) ? vry[n + t + 1].x : 0.0f;
    const float vy2 = (t + 2 < lim) ? vry[n + t + 2].x : 0.0f;
    const float vy3 = (t + 3 < lim) ? vry[n + t + 3].x : 0.0f;

    const float p0 = sqrtf(fmaxf(vxA.x, 0.0f) * fmaxf(vy0, 0.0f));
    const float p1 = sqrtf(fmaxf(vxA.z, 0.0f) * fmaxf(vy1, 0.0f));
    const float p2 = sqrtf(fmaxf(vxB.x, 0.0f) * fmaxf(vy2, 0.0f));
    const float p3 = sqrtf(fmaxf(vxB.z, 0.0f) * fmaxf(vy3, 0.0f));

    const float r0 = fminf(fmaxf(kvA.x * __builtin_amdgcn_rcpf(fmaxf(p0, EPS_F)), -RHO_LIM_F), RHO_LIM_F);
    const float r1 = fminf(fmaxf(kvA.z * __builtin_amdgcn_rcpf(fmaxf(p1, EPS_F)), -RHO_LIM_F), RHO_LIM_F);
    const float r2 = fminf(fmaxf(kvB.x * __builtin_amdgcn_rcpf(fmaxf(p2, EPS_F)), -RHO_LIM_F), RHO_LIM_F);
    const float r3 = fminf(fmaxf(kvB.z * __builtin_amdgcn_rcpf(fmaxf(p3, EPS_F)), -RHO_LIM_F), RHO_LIM_F);

    float4 c0v, cnv;
    if (one_m == 0.0f) {
        // FAST PATH (exact when (1-a)^2 == 0): theta/s terms vanish.
        const float hc = 0.5f * coef;
        c0v.x = p0 * r0 * hc;  c0v.y = p1 * r1 * hc;
        c0v.z = p2 * r2 * hc;  c0v.w = p3 * r3 * hc;
        cnv.x = hc * kvA.y;    cnv.y = hc * kvA.w;
        cnv.z = hc * kvB.y;    cnv.w = hc * kvB.w;
    } else {
        // GENERAL PATH
        const float th0 = acosf(r0), th1 = acosf(r1), th2 = acosf(r2), th3 = acosf(r3);
        const float s0 = sqrtf(1.0f - r0 * r0), s1 = sqrtf(1.0f - r1 * r1);
        const float s2 = sqrtf(1.0f - r2 * r2), s3 = sqrtf(1.0f - r3 * r3);
        const float br0 = coef * PI_F - one_m * th0;
        const float br1 = coef * PI_F - one_m * th1;
        const float br2 = coef * PI_F - one_m * th2;
        const float br3 = coef * PI_F - one_m * th3;
        c0v.x = p0 * inv2pi * (one_m * s0 + r0 * br0);
        c0v.y = p1 * inv2pi * (one_m * s1 + r1 * br1);
        c0v.z = p2 * inv2pi * (one_m * s2 + r2 * br2);
        c0v.w = p3 * inv2pi * (one_m * s3 + r3 * br3);
        cnv.x = br0 * inv2pi * kvA.y;
        cnv.y = br1 * inv2pi * kvA.w;
        cnv.z = br2 * inv2pi * kvB.y;
        cnv.w = br3 * inv2pi * kvB.w;
    }

    ((float4*)&sc0[4])[tid] = c0v;
    ((float4*)&scn[4])[tid] = cnv;

    __syncthreads();

    // ---- phase 2: 3-tap conv + combine + store ----
    const float c0l = sc0[t + 3];
    const float c0r = sc0[t + 8];
    const float cnl = scn[t + 3];
    const float cnr = scn[t + 8];
    const float4 m0 = ((const float4*)&sc0[4])[tid];
    const float4 m1 = ((const float4*)&scn[4])[tid];

    const float kg0 = w0 * c0l  + w1 * m0.x + w2 * m0.y;
    const float kg1 = w0 * m0.x + w1 * m0.y + w2 * m0.z;
    const float kg2 = w0 * m0.y + w1 * m0.z + w2 * m0.w;
    const float kg3 = w0 * m0.z + w1 * m0.w + w2 * c0r;

    const float kn0 = w0 * cnl  + w1 * m1.x + w2 * m1.y + kg0;
    const float kn1 = w0 * m1.x + w1 * m1.y + w2 * m1.z + kg1;
    const float kn2 = w0 * m1.y + w1 * m1.z + w2 * m1.w + kg2;
    const float kn3 = w0 * m1.z + w1 * m1.w + w2 * cnr  + kg3;

    float4* orow = (float4*)(out + (size_t)row * TDIM * 2);
    float4 oA, oB;
    oA.x = kg0 + bia; oA.y = kn0 + bia; oA.z = kg1 + bia; oA.w = kn1 + bia;
    oB.x = kg2 + bia; oB.y = kn2 + bia; oB.z = kg3 + bia; oB.w = kn3 + bia;
    orow[2 * tid]     = oA;
    orow[2 * tid + 1] = oB;
}

extern "C" void kernel_launch(void* const* d_in, const int* in_sizes, int n_in,
                              void* d_out, int out_size, void* d_ws, size_t ws_size,
                              hipStream_t stream) {
    const float* k     = (const float*)d_in[0];
    const float* leak  = (const float*)d_in[1];
    const float* alpha = (const float*)d_in[2];
    const float* beta  = (const float*)d_in[3];
    float* out = (float*)d_out;

    const int n_rows = BDIM * BDIM * NDIM;   // 8192
    conv_arccos_kernel<<<n_rows, TPB, 0, stream>>>(k, leak, alpha, beta, out);
}

// Round 4
// 126.136 us; speedup vs baseline: 1.0817x; 1.0817x over previous
//
#include <hip/hip_runtime.h>
#include <math.h>

#define BDIM 8
#define NDIM 128
#define TDIM 1024
#define TPB 512   // one block per row; each thread owns element pair (t, t+1)

#define EPS_F 1e-12f
#define RHO_LIM_F (1.0f - 1e-6f)
#define PI_F 3.14159265358979323846f

// One block per (b1,b2,n) row of T=1024. Thread tid handles elements
// t = 2*tid, t+1: exactly one float4 of k (kgp0,kntk0,kgp1,kntk1) and one
// float4 of out (kg0,kn0,kg1,kn1). LDS holds c0 / c1*k_ntk at index t+1
// (zero halos at 0 and TDIM+1); stores and conv reads are scalar stride-2
// across lanes -> 2-way bank aliasing, which is free on gfx950 (m136).

__global__ __launch_bounds__(TPB) void conv_arccos_kernel(
    const float* __restrict__ k,      // (B,B,N,T,2)
    const float* __restrict__ leak,   // scalar
    const float* __restrict__ alpha,  // (3,)
    const float* __restrict__ beta,   // scalar
    float* __restrict__ out)          // (B,B,N,T,2)
{
    __shared__ float sc0[TDIM + 2];
    __shared__ float scn[TDIM + 2];

    const int row = blockIdx.x;           // 0 .. B*B*N-1
    const int n   = row % NDIM;
    const int bb  = row / NDIM;
    const int b2  = bb % BDIM;
    const int b1  = bb / BDIM;
    const int tid = threadIdx.x;
    const int t   = tid * 2;

    // forward value of clamp_pg(x) is max(x, 0)
    const float a   = fmaxf(leak[0], 0.0f);
    const float w0  = fmaxf(alpha[0], 0.0f);
    const float w1  = fmaxf(alpha[1], 0.0f);
    const float w2  = fmaxf(alpha[2], 0.0f);
    const float bia = fmaxf(beta[0], 0.0f);

    const float one_m  = (1.0f - a) * (1.0f - a);
    const float coef   = 1.0f + a * a;
    const float inv2pi = 0.15915494309189535f;

    const float4* krow4 = (const float4*)(k + (size_t)row * TDIM * 2);
    // v[b, t] = k[b, b, 0, t, 0]
    const float2* vrx = (const float2*)(k) + (size_t)(b1 * BDIM + b1) * NDIM * TDIM;
    const float2* vry = (const float2*)(k) + (size_t)(b2 * BDIM + b2) * NDIM * TDIM;

    // zero conv halos
    if (tid == 0) { sc0[0] = 0.0f; scn[0] = 0.0f; sc0[TDIM + 1] = 0.0f; scn[TDIM + 1] = 0.0f; }

    // ---- phase 1: elementwise transform, 2 elems/thread, all coalesced ----
    const float4 kv  = krow4[tid];                    // kgp0,kntk0,kgp1,kntk1
    const float4 vx2 = ((const float4*)vrx)[tid];     // vx[t] (.x), vx[t+1] (.z)

    const int lim = TDIM - n;  // vy in-bounds iff t+i < lim
    const float vy0 = (t     < lim) ? vry[n + t    ].x : 0.0f;
    const float vy1 = (t + 1 < lim) ? vry[n + t + 1].x : 0.0f;

    const float p0 = sqrtf(fmaxf(vx2.x, 0.0f) * fmaxf(vy0, 0.0f));
    const float p1 = sqrtf(fmaxf(vx2.z, 0.0f) * fmaxf(vy1, 0.0f));

    const float r0 = fminf(fmaxf(kv.x * __builtin_amdgcn_rcpf(fmaxf(p0, EPS_F)), -RHO_LIM_F), RHO_LIM_F);
    const float r1 = fminf(fmaxf(kv.z * __builtin_amdgcn_rcpf(fmaxf(p1, EPS_F)), -RHO_LIM_F), RHO_LIM_F);

    float c00, c01, cn0, cn1;
    if (one_m == 0.0f) {
        // FAST PATH (exact when (1-a)^2 == 0): theta/s terms vanish.
        // c0 = prod * rho * coef/2 ;  c1 = coef/2
        const float hc = 0.5f * coef;
        c00 = p0 * r0 * hc;
        c01 = p1 * r1 * hc;
        cn0 = hc * kv.y;
        cn1 = hc * kv.w;
    } else {
        // GENERAL PATH
        const float th0 = acosf(r0), th1 = acosf(r1);
        const float s0 = sqrtf(1.0f - r0 * r0), s1 = sqrtf(1.0f - r1 * r1);
        const float br0 = coef * PI_F - one_m * th0;
        const float br1 = coef * PI_F - one_m * th1;
        c00 = p0 * inv2pi * (one_m * s0 + r0 * br0);
        c01 = p1 * inv2pi * (one_m * s1 + r1 * br1);
        cn0 = br0 * inv2pi * kv.y;
        cn1 = br1 * inv2pi * kv.w;
    }

    sc0[t + 1] = c00;
    sc0[t + 2] = c01;
    scn[t + 1] = cn0;
    scn[t + 2] = cn1;

    __syncthreads();

    // ---- phase 2: 3-tap conv + combine + coalesced float4 store ----
    const float c0l = sc0[t];
    const float c0r = sc0[t + 3];
    const float cnl = scn[t];
    const float cnr = scn[t + 3];

    const float kg0 = w0 * c0l + w1 * c00 + w2 * c01;
    const float kg1 = w0 * c00 + w1 * c01 + w2 * c0r;
    const float kn0 = w0 * cnl + w1 * cn0 + w2 * cn1 + kg0;
    const float kn1 = w0 * cn0 + w1 * cn1 + w2 * cnr + kg1;

    float4 o;
    o.x = kg0 + bia;
    o.y = kn0 + bia;
    o.z = kg1 + bia;
    o.w = kn1 + bia;
    ((float4*)(out + (size_t)row * TDIM * 2))[tid] = o;
}

extern "C" void kernel_launch(void* const* d_in, const int* in_sizes, int n_in,
                              void* d_out, int out_size, void* d_ws, size_t ws_size,
                              hipStream_t stream) {
    const float* k     = (const float*)d_in[0];
    const float* leak  = (const float*)d_in[1];
    const float* alpha = (const float*)d_in[2];
    const float* beta  = (const float*)d_in[3];
    float* out = (float*)d_out;

    const int n_rows = BDIM * BDIM * NDIM;   // 8192
    conv_arccos_kernel<<<n_rows, TPB, 0, stream>>>(k, leak, alpha, beta, out);
}